// Round 1
// baseline (173.151 us; speedup 1.0000x reference)
//
#include <hip/hip_runtime.h>

// RandomCutout: B=32, H=512, W=512, C=3, 2 masks of 128x128 per image.
// out[b,y,x,c] = in[b,y,x,c] unless (y,x) falls in any of the 2 clipped
// rectangles for batch b, in which case 0.

#define BB 32
#define HH 512
#define WW 512
#define CC 3
#define MH 128
#define MW 128

// floats per image = 512*512*3 = 786432 ; float4 per image = 196608
// floats per row = 1536 ; float4 per row = 384  (divisible by 4: no row spans)
#define PER_IMG4 196608
#define ROW4 384
#define TOTAL4 (BB * PER_IMG4)   // 6,291,456

__global__ __launch_bounds__(256)
void RandomCutout_59545426592097_kernel(const float4* __restrict__ in,
                                        const int* __restrict__ cys,
                                        const int* __restrict__ cxs,
                                        float4* __restrict__ out) {
    int g = blockIdx.x * blockDim.x + threadIdx.x;   // < TOTAL4, exact grid
    int b   = g / PER_IMG4;
    int rem = g - b * PER_IMG4;
    int y   = rem / ROW4;
    int off = (rem - y * ROW4) * 4;   // float offset within row, [0,1536)

    // Per-batch mask rectangles (clipped). 2 masks.
    int cy0 = cys[b * 2 + 0], cy1 = cys[b * 2 + 1];
    int cx0 = cxs[b * 2 + 0], cx1 = cxs[b * 2 + 1];
    int y1a = max(cy0 - MH / 2, 0), y2a = min(cy0 + MH / 2, HH);
    int y1b = max(cy1 - MH / 2, 0), y2b = min(cy1 + MH / 2, HH);
    int x1a = max(cx0 - MW / 2, 0), x2a = min(cx0 + MW / 2, WW);
    int x1b = max(cx1 - MW / 2, 0), x2b = min(cx1 + MW / 2, WW);

    bool yin_a = (y >= y1a) & (y < y2a);
    bool yin_b = (y >= y1b) & (y < y2b);

    float4 v = in[g];

    if (yin_a | yin_b) {
        // Column index for each of the 4 floats (channel-interleaved, /3).
        int xc0 = (off + 0) / 3;
        int xc1 = (off + 1) / 3;
        int xc2 = (off + 2) / 3;
        int xc3 = (off + 3) / 3;

        bool c0 = (yin_a & (xc0 >= x1a) & (xc0 < x2a)) | (yin_b & (xc0 >= x1b) & (xc0 < x2b));
        bool c1 = (yin_a & (xc1 >= x1a) & (xc1 < x2a)) | (yin_b & (xc1 >= x1b) & (xc1 < x2b));
        bool c2 = (yin_a & (xc2 >= x1a) & (xc2 < x2a)) | (yin_b & (xc2 >= x1b) & (xc2 < x2b));
        bool c3 = (yin_a & (xc3 >= x1a) & (xc3 < x2a)) | (yin_b & (xc3 >= x1b) & (xc3 < x2b));

        if (c0) v.x = 0.0f;
        if (c1) v.y = 0.0f;
        if (c2) v.z = 0.0f;
        if (c3) v.w = 0.0f;
    }

    out[g] = v;
}

extern "C" void kernel_launch(void* const* d_in, const int* in_sizes, int n_in,
                              void* d_out, int out_size, void* d_ws, size_t ws_size,
                              hipStream_t stream) {
    const float4* in  = (const float4*)d_in[0];
    const int*    cys = (const int*)d_in[1];
    const int*    cxs = (const int*)d_in[2];
    float4*       out = (float4*)d_out;

    const int threads = 256;
    const int blocks  = TOTAL4 / threads;   // 24576, exact
    RandomCutout_59545426592097_kernel<<<blocks, threads, 0, stream>>>(in, cys, cxs, out);
}